// Round 1
// baseline (88.912 us; speedup 1.0000x reference)
//
#include <hip/hip_runtime.h>
#include <hip/hip_bf16.h>

// Decorrelation: out[n,v] = x[n,v] + sum_{c<v} x[n,c] * S_{c,v}(x[n,c])
// where S is a uniform cubic B-spline with coefficients params[:, l(v,c)],
// l(v,c) = v(v-1)/2 + c. Uniform knots => closed-form basis; fold the
// basis-dot-params into a per-(segment, pair) cubic coefficient table in LDS.

constexpr int D    = 16;
constexpr int K    = 11;          // params rows (degree+1)
constexpr int L    = 120;         // D*(D-1)/2
constexpr int NSEG = 8;           // K - SPLINE_DEG
// per-segment LDS stride in floats: 120 cells * 4 + 4 pad => 484.
// dword index = s*484 + 4l : 484 % 32 == 4, so the 8 segment values map to
// disjoint bank quads -> conflict-free ds_read_b128.
constexpr int SEG_STRIDE = L * 4 + 4;

__global__ __launch_bounds__(256) void decor_kernel(
    const float* __restrict__ x, const float* __restrict__ params,
    const float* __restrict__ prange, float* __restrict__ out, int N) {
  __shared__ float T[NSEG * SEG_STRIDE];  // 15488 B

  // Build coefficient table: S(u) = c0 + c1 u + c2 u^2 + c3 u^3 on segment s.
  for (int idx = threadIdx.x; idx < NSEG * L; idx += 256) {
    int s = idx / L;
    int l = idx - s * L;
    float p0 = params[(s + 0) * L + l];
    float p1 = params[(s + 1) * L + l];
    float p2 = params[(s + 2) * L + l];
    float p3 = params[(s + 3) * L + l];
    float* c = &T[s * SEG_STRIDE + l * 4];
    c[0] = (p0 + 4.0f * p1 + p2) * (1.0f / 6.0f);
    c[1] = (p2 - p0) * 0.5f;
    c[2] = (p0 - 2.0f * p1 + p2) * 0.5f;
    c[3] = (p3 - p0) * (1.0f / 6.0f) + (p1 - p2) * 0.5f;
  }
  __syncthreads();

  int n = blockIdx.x * 256 + threadIdx.x;
  if (n >= N) return;

  // Load one sample row (coalesced float4s).
  float xv[D];
  const float4* xr = reinterpret_cast<const float4*>(x + (size_t)n * D);
#pragma unroll
  for (int i = 0; i < D / 4; ++i) {
    float4 v = xr[i];
    xv[4 * i + 0] = v.x; xv[4 * i + 1] = v.y;
    xv[4 * i + 2] = v.z; xv[4 * i + 3] = v.w;
  }

  // Per-dim: segment byte-offset-ish index and x * [1,u,u^2,u^3].
  int   soff[D];
  float w1[D], w2[D], w3[D];
#pragma unroll
  for (int d = 0; d < D; ++d) {
    float lo0  = prange[d];
    float hi0  = prange[D + d];
    float span = hi0 - lo0;
    float lo   = lo0 - 0.1f * span;
    float hi   = hi0 + 0.1f * span;
    float eps  = 1e-6f * (hi - lo);
    float hinv = (float)NSEG / (hi - lo);
    float xc   = fminf(fmaxf(xv[d], lo), hi - eps);
    float t    = (xc - lo) * hinv;          // in [0, 8)
    int   s    = (int)t;
    s          = s > NSEG - 1 ? NSEG - 1 : s;
    float u    = t - (float)s;
    soff[d]    = s * SEG_STRIDE;
    w1[d] = xv[d] * u;
    w2[d] = w1[d] * u;
    w3[d] = w2[d] * u;
  }

  float acc[D];
#pragma unroll
  for (int v = 0; v < D; ++v) acc[v] = xv[v];

#pragma unroll
  for (int v = 1; v < D; ++v) {
    const int lbase = v * (v - 1) / 2;
#pragma unroll
    for (int c = 0; c < v; ++c) {
      const float4 cf =
          *reinterpret_cast<const float4*>(&T[soff[c] + (lbase + c) * 4]);
      float a = acc[v];
      a = fmaf(cf.x, xv[c], a);
      a = fmaf(cf.y, w1[c], a);
      a = fmaf(cf.z, w2[c], a);
      a = fmaf(cf.w, w3[c], a);
      acc[v] = a;
    }
  }

  float4* orow = reinterpret_cast<float4*>(out + (size_t)n * D);
#pragma unroll
  for (int i = 0; i < D / 4; ++i) {
    orow[i] = make_float4(acc[4 * i + 0], acc[4 * i + 1],
                          acc[4 * i + 2], acc[4 * i + 3]);
  }
}

// Penalties: d2 = sum((p[i+2L]-2p[i+L]+p[i])^2), d1 = sum((p[i+L]-p[i])^2),
// pp = sum(p^2). Output order: [second_order, first_order, param_pen].
__global__ __launch_bounds__(256) void pen_kernel(const float* __restrict__ p,
                                                  float* __restrict__ o) {
  float s2 = 0.0f, s1 = 0.0f, s0 = 0.0f;
  for (int i = threadIdx.x; i < (K - 2) * L; i += 256) {
    float v = p[i + 2 * L] - 2.0f * p[i + L] + p[i];
    s2 += v * v;
  }
  for (int i = threadIdx.x; i < (K - 1) * L; i += 256) {
    float v = p[i + L] - p[i];
    s1 += v * v;
  }
  for (int i = threadIdx.x; i < K * L; i += 256) {
    float v = p[i];
    s0 += v * v;
  }
#pragma unroll
  for (int off = 32; off > 0; off >>= 1) {
    s2 += __shfl_down(s2, off);
    s1 += __shfl_down(s1, off);
    s0 += __shfl_down(s0, off);
  }
  __shared__ float r[3][4];
  int wid = threadIdx.x >> 6, lane = threadIdx.x & 63;
  if (lane == 0) { r[0][wid] = s2; r[1][wid] = s1; r[2][wid] = s0; }
  __syncthreads();
  if (threadIdx.x == 0) {
    o[0] = r[0][0] + r[0][1] + r[0][2] + r[0][3];
    o[1] = r[1][0] + r[1][1] + r[1][2] + r[1][3];
    o[2] = r[2][0] + r[2][1] + r[2][2] + r[2][3];
  }
}

extern "C" void kernel_launch(void* const* d_in, const int* in_sizes, int n_in,
                              void* d_out, int out_size, void* d_ws,
                              size_t ws_size, hipStream_t stream) {
  const float* x      = (const float*)d_in[0];
  const float* params = (const float*)d_in[1];
  const float* prange = (const float*)d_in[2];
  float* out = (float*)d_out;
  int N = in_sizes[0] / D;

  pen_kernel<<<1, 256, 0, stream>>>(params, out + (size_t)N * D);
  int blocks = (N + 255) / 256;
  decor_kernel<<<blocks, 256, 0, stream>>>(x, params, prange, out, N);
}

// Round 6
// 83.119 us; speedup vs baseline: 1.0697x; 1.0697x over previous
//
#include <hip/hip_runtime.h>
#include <hip/hip_bf16.h>

// Decorrelation: out[n,v] = x[n,v] + sum_{c<v} x[n,c] * S_{c,v}(x[n,c])
// Uniform knots => closed-form cubic B-spline; fold basis·params into a
// per-(segment, pair) cubic coefficient table in LDS, evaluate via Horner.
// Penalties fused into block 0.

constexpr int D    = 16;
constexpr int K    = 11;          // params rows (degree+1)
constexpr int L    = 120;         // D*(D-1)/2
constexpr int NSEG = 8;           // K - SPLINE_DEG
// per-segment LDS stride in floats: 120 cells * 4 + 4 pad => 484.
// dword index = s*484 + 4l : 484 % 32 == 4, so the 8 segment values map to
// disjoint bank quads -> conflict-free ds_read_b128.
constexpr int SEG_STRIDE = L * 4 + 4;

__global__ __launch_bounds__(256) void decor_fused(
    const float* __restrict__ x, const float* __restrict__ params,
    const float* __restrict__ prange, float* __restrict__ out, int N) {
  __shared__ float T[NSEG * SEG_STRIDE];  // 15488 B

  // Build coefficient table: S(u) = c0 + c1 u + c2 u^2 + c3 u^3 on segment s.
  for (int idx = threadIdx.x; idx < NSEG * L; idx += 256) {
    int s = idx / L;
    int l = idx - s * L;
    float p0 = params[(s + 0) * L + l];
    float p1 = params[(s + 1) * L + l];
    float p2 = params[(s + 2) * L + l];
    float p3 = params[(s + 3) * L + l];
    float* c = &T[s * SEG_STRIDE + l * 4];
    c[0] = (p0 + 4.0f * p1 + p2) * (1.0f / 6.0f);
    c[1] = (p2 - p0) * 0.5f;
    c[2] = (p0 - 2.0f * p1 + p2) * 0.5f;
    c[3] = (p3 - p0) * (1.0f / 6.0f) + (p1 - p2) * 0.5f;
  }

  // Penalties in block 0 only (out layout: [N*D main, s2, s1, s0]).
  if (blockIdx.x == 0) {
    float s2 = 0.0f, s1 = 0.0f, s0 = 0.0f;
    for (int i = threadIdx.x; i < (K - 2) * L; i += 256) {
      float v = params[i + 2 * L] - 2.0f * params[i + L] + params[i];
      s2 += v * v;
    }
    for (int i = threadIdx.x; i < (K - 1) * L; i += 256) {
      float v = params[i + L] - params[i];
      s1 += v * v;
    }
    for (int i = threadIdx.x; i < K * L; i += 256) {
      float v = params[i];
      s0 += v * v;
    }
#pragma unroll
    for (int off = 32; off > 0; off >>= 1) {
      s2 += __shfl_down(s2, off);
      s1 += __shfl_down(s1, off);
      s0 += __shfl_down(s0, off);
    }
    __shared__ float r[3][4];
    int wid = threadIdx.x >> 6, lane = threadIdx.x & 63;
    if (lane == 0) { r[0][wid] = s2; r[1][wid] = s1; r[2][wid] = s0; }
    __syncthreads();
    if (threadIdx.x == 0) {
      float* o = out + (size_t)N * D;
      o[0] = r[0][0] + r[0][1] + r[0][2] + r[0][3];
      o[1] = r[1][0] + r[1][1] + r[1][2] + r[1][3];
      o[2] = r[2][0] + r[2][1] + r[2][2] + r[2][3];
    }
  }
  __syncthreads();

  int n = blockIdx.x * 256 + threadIdx.x;
  if (n >= N) return;

  // Load one sample row (coalesced float4s).
  float xv[D];
  const float4* xr = reinterpret_cast<const float4*>(x + (size_t)n * D);
#pragma unroll
  for (int i = 0; i < D / 4; ++i) {
    float4 v = xr[i];
    xv[4 * i + 0] = v.x; xv[4 * i + 1] = v.y;
    xv[4 * i + 2] = v.z; xv[4 * i + 3] = v.w;
  }

  // Per-dim: local coordinate u and segment BYTE offset into T.
  float u[D];
  int   sb[D];
#pragma unroll
  for (int d = 0; d < D; ++d) {
    float lo0  = prange[d];
    float hi0  = prange[D + d];
    float span = hi0 - lo0;
    float lo   = lo0 - 0.1f * span;
    float hi   = hi0 + 0.1f * span;
    float eps  = 1e-6f * (hi - lo);
    float hinv = (float)NSEG / (hi - lo);
    float xc   = fminf(fmaxf(xv[d], lo), hi - eps);
    float t    = (xc - lo) * hinv;          // in [0, 8)
    int   s    = (int)t;
    s          = s > NSEG - 1 ? NSEG - 1 : s;
    u[d]       = t - (float)s;
    sb[d]      = s * (SEG_STRIDE * 4);      // byte offset
  }

  float acc[D];
#pragma unroll
  for (int v = 0; v < D; ++v) acc[v] = xv[v];

  const char* Tb = reinterpret_cast<const char*>(T);
#pragma unroll
  for (int v = 1; v < D; ++v) {
    const int lbase = v * (v - 1) / 2;
#pragma unroll
    for (int c = 0; c < v; ++c) {
      const float4 cf =
          *reinterpret_cast<const float4*>(Tb + sb[c] + (lbase + c) * 16);
      // Horner: q = c0 + u(c1 + u(c2 + u*c3)); acc += q * x_c
      float q = fmaf(fmaf(fmaf(cf.w, u[c], cf.z), u[c], cf.y), u[c], cf.x);
      acc[v] = fmaf(q, xv[c], acc[v]);
    }
  }

  float4* orow = reinterpret_cast<float4*>(out + (size_t)n * D);
#pragma unroll
  for (int i = 0; i < D / 4; ++i) {
    orow[i] = make_float4(acc[4 * i + 0], acc[4 * i + 1],
                          acc[4 * i + 2], acc[4 * i + 3]);
  }
}

extern "C" void kernel_launch(void* const* d_in, const int* in_sizes, int n_in,
                              void* d_out, int out_size, void* d_ws,
                              size_t ws_size, hipStream_t stream) {
  const float* x      = (const float*)d_in[0];
  const float* params = (const float*)d_in[1];
  const float* prange = (const float*)d_in[2];
  float* out = (float*)d_out;
  int N = in_sizes[0] / D;

  int blocks = (N + 255) / 256;
  decor_fused<<<blocks, 256, 0, stream>>>(x, params, prange, out, N);
}